// Round 8
// baseline (185.028 us; speedup 1.0000x reference)
//
#include <hip/hip_runtime.h>
#include <hip/hip_bf16.h>

// GraphConv: out = relu( segment_sum(x[src], dst) @ W_rel^T + b_rel + x @ W_root^T )
// N = 50000, F = 128, E = 800000.
//
// R8: occupancy + dispatch-count attack.
//   - NPB 32 -> 16: 3125 blocks (was 1563; occupancy 52% -> wave-slot-limited)
//   - fuse bf16 converts into the bin kernel (independent work, one dispatch)
// Pipeline: memsetAsync(cursors) -> prep_bin -> agg_gemm.  (3 dispatches)

#define F 128
#define NPB 16              // nodes per bucket (50000 = 3125 * 16 exactly)
#define NPARTS 8            // write partitions (blockIdx%8 ~ XCD heuristic)
#define CAP 96              // slots per (part,bucket); mean 32 -> +11 sigma
#define CAPB 448            // LDS edge slots per bucket; mean 256 -> +12 sigma
#define AST 68              // A-tile row stride in uints (136 bf16; 16B-aligned
                            // rows, 4-bank rotate -> <=2-way LDS conflicts)

typedef __bf16 bf16x8 __attribute__((ext_vector_type(8)));
typedef float f32x4 __attribute__((ext_vector_type(4)));

__device__ inline unsigned f32_to_bf16_rne(float f) {
  unsigned u = __float_as_uint(f);
  unsigned r = u + 0x7fffu + ((u >> 16) & 1u);
  return r >> 16;
}
__device__ inline unsigned pack2(float2 v) {
  return f32_to_bf16_rne(v.x) | (f32_to_bf16_rne(v.y) << 16);
}

// ---------------------------------------------------------------------------
// Kernel 1: fused bf16 convert (x, Wrel, Wroot) + edge binning by dst>>4.
// Cursor array is zeroed by hipMemsetAsync before this kernel.
// ---------------------------------------------------------------------------
__global__ __launch_bounds__(256) void prep_bin_kernel(
    const float2* __restrict__ x, const float2* __restrict__ w0,
    const float2* __restrict__ w1, const int* __restrict__ ei,
    unsigned* __restrict__ xb, unsigned* __restrict__ wb,
    int* __restrict__ binCursor, unsigned* __restrict__ bin,
    int E, int NB, int n2x, int n2w) {
  const int tid0 = blockIdx.x * blockDim.x + threadIdx.x;
  const int stride = gridDim.x * blockDim.x;

  // --- converts (grid-stride)
  const int totalc = n2x + 2 * n2w;
  for (int i = tid0; i < totalc; i += stride) {
    if (i < n2x) {
      xb[i] = pack2(x[i]);
    } else if (i < n2x + n2w) {
      int j = i - n2x;
      wb[j] = pack2(w0[j]);
    } else {
      int j = i - n2x - n2w;
      wb[n2w + j] = pack2(w1[j]);
    }
  }

  // --- binning (grid-stride); partition by blockIdx%8 for XCD write locality
  const int part = blockIdx.x & (NPARTS - 1);
  for (int e = tid0; e < E; e += stride) {
    unsigned src = (unsigned)ei[e];
    unsigned dst = (unsigned)ei[E + e];
    unsigned key = (dst << 16) | src;
    int cell = part * NB + (int)(dst >> 4);
    int slot = atomicAdd(&binCursor[cell], 1);
    if (slot < CAP) bin[(size_t)cell * CAP + slot] = key;
  }
}

// ---------------------------------------------------------------------------
// Kernel 2: per-bucket LDS counting sort + wave-per-node register gather
//           -> bf16 A-tile in LDS -> fused dual MFMA GEMM + bias + ReLU.
// One block per 16-node bucket; 3125 blocks.
// ---------------------------------------------------------------------------
__global__ __launch_bounds__(256) void agg_gemm_kernel(
    const unsigned* __restrict__ xb, const unsigned* __restrict__ bin,
    const int* __restrict__ binCursor, const __bf16* __restrict__ wb,
    const float* __restrict__ brel, float* __restrict__ out, int N, int NB) {
  __shared__ int cntS[NPB];
  __shared__ int offS[NPB];
  __shared__ int curS[NPB];
  __shared__ unsigned short eLds[CAPB];
  __shared__ unsigned aLds[NPB * AST];  // 16 rows x 128 bf16 (padded)
  const int b = blockIdx.x;
  const int t = threadIdx.x;

  if (t < NPB) cntS[t] = 0;
  __syncthreads();

  // --- stage edges into registers + LDS histogram by local node id
  unsigned kreg[NPARTS];
  int cnt_p[NPARTS];
#pragma unroll
  for (int p = 0; p < NPARTS; ++p) {
    int cell = p * NB + b;
    int c = min(binCursor[cell], CAP);
    cnt_p[p] = c;
    if (t < c) {
      kreg[p] = bin[(size_t)cell * CAP + t];
      atomicAdd(&cntS[(kreg[p] >> 16) & (NPB - 1)], 1);
    }
  }
  __syncthreads();

  // --- exclusive scan of 16 counts (first wave)
  if (t < 64) {
    int v = (t < NPB) ? cntS[t] : 0;
    int incl = v;
#pragma unroll
    for (int off = 1; off < NPB; off <<= 1) {
      int u = __shfl_up(incl, off);
      if ((t & 63) >= off) incl += u;
    }
    if (t < NPB) {
      offS[t] = incl - v;
      curS[t] = incl - v;
    }
  }
  __syncthreads();

  // --- scatter srcs into LDS, grouped by local node id
#pragma unroll
  for (int p = 0; p < NPARTS; ++p) {
    if (t < cnt_p[p]) {
      int d = (kreg[p] >> 16) & (NPB - 1);
      int pos = atomicAdd(&curS[d], 1);
      if (pos < CAPB) eLds[pos] = (unsigned short)(kreg[p] & 0xffffu);
    }
  }
  __syncthreads();

  // --- wave-per-node gather-accumulate -> bf16 A-tile row in LDS
  const int wave = t >> 6;
  const int lane = t & 63;
  const int nodeBase = b * NPB;
#pragma unroll
  for (int di = wave; di < NPB; di += 4) {
    float ax = 0.f, ay = 0.f;
    int beg = min(offS[di], CAPB);
    int end = min(offS[di] + cntS[di], CAPB);
    int e = beg;
    for (; e + 3 < end; e += 4) {
      int s0 = eLds[e + 0];
      int s1 = eLds[e + 1];
      int s2 = eLds[e + 2];
      int s3 = eLds[e + 3];
      unsigned v0 = xb[(size_t)s0 * 64 + lane];
      unsigned v1 = xb[(size_t)s1 * 64 + lane];
      unsigned v2 = xb[(size_t)s2 * 64 + lane];
      unsigned v3 = xb[(size_t)s3 * 64 + lane];
      ax += __uint_as_float(v0 << 16);
      ay += __uint_as_float(v0 & 0xffff0000u);
      ax += __uint_as_float(v1 << 16);
      ay += __uint_as_float(v1 & 0xffff0000u);
      ax += __uint_as_float(v2 << 16);
      ay += __uint_as_float(v2 & 0xffff0000u);
      ax += __uint_as_float(v3 << 16);
      ay += __uint_as_float(v3 & 0xffff0000u);
    }
    for (; e < end; ++e) {
      unsigned v = xb[(size_t)eLds[e] * 64 + lane];
      ax += __uint_as_float(v << 16);
      ay += __uint_as_float(v & 0xffff0000u);
    }
    aLds[di * AST + lane] = f32_to_bf16_rne(ax) | (f32_to_bf16_rne(ay) << 16);
  }
  __syncthreads();

  // --- fused dual GEMM: M=16 (bucket nodes), Ncols=128, K=128, 2 phases.
  // Wave w owns cols [32w, 32w+32): nt = 2w+s, s in {0,1}.
  const int m16 = lane & 15;
  const int quad = lane >> 4;
  const f32x4 zero4 = {0.f, 0.f, 0.f, 0.f};
  const bf16x8 zero8 = {};
  f32x4 acc[2];
  acc[0] = zero4;
  acc[1] = zero4;

#pragma unroll
  for (int ph = 0; ph < 2; ++ph) {
    const __bf16* __restrict__ W = wb + (size_t)ph * F * F;  // 0=Wrel, 1=Wroot
#pragma unroll
    for (int k0 = 0; k0 < F; k0 += 32) {
      const int kcol = k0 + 8 * quad;
      bf16x8 a, bw[2];
      if (ph == 0) {
        a = *(const bf16x8*)&aLds[m16 * AST + (kcol >> 1)];
      } else {
        int row = nodeBase + m16;
        a = (row < N)
                ? *(const bf16x8*)((const __bf16*)xb + (size_t)row * F + kcol)
                : zero8;
      }
#pragma unroll
      for (int s = 0; s < 2; ++s) {
        int nt = wave * 2 + s;
        bw[s] = *(const bf16x8*)(W + (size_t)(nt * 16 + m16) * F + kcol);
      }
#pragma unroll
      for (int s = 0; s < 2; ++s)
        acc[s] = __builtin_amdgcn_mfma_f32_16x16x32_bf16(a, bw[s], acc[s], 0, 0, 0);
    }
  }

  // --- epilogue: bias + ReLU + store (C/D: col=lane&15, row=quad*4+reg)
#pragma unroll
  for (int s = 0; s < 2; ++s) {
    int nt = wave * 2 + s;
    float bias = brel[nt * 16 + m16];
    int row0 = nodeBase + quad * 4;
#pragma unroll
    for (int r = 0; r < 4; ++r) {
      int row = row0 + r;
      if (row < N)
        out[(size_t)row * F + nt * 16 + m16] = fmaxf(acc[s][r] + bias, 0.f);
    }
  }
}

// ===========================================================================
// Fallback (tiny ws): fp32 atomics into out + fused fp32 GEMM in-place
// ===========================================================================
__global__ __launch_bounds__(256) void scatter_add_kernel(
    const float4* __restrict__ x4, const int* __restrict__ ei,
    float* __restrict__ agg, int E) {
  int gid = blockIdx.x * blockDim.x + threadIdx.x;
  if (gid >= E * 32) return;
  int e = gid >> 5, q = gid & 31;
  float4 v = x4[(size_t)ei[e] * 32 + q];
  float* a = agg + (size_t)ei[E + e] * F + q * 4;
  atomicAdd(a + 0, v.x);
  atomicAdd(a + 1, v.y);
  atomicAdd(a + 2, v.z);
  atomicAdd(a + 3, v.w);
}

#define ROWS_PER_BLOCK 64
#define SA_STRIDE 36
#define SW_STRIDE 132

__global__ __launch_bounds__(256) void gemm_fused_kernel(
    const float* __restrict__ agg, const float* __restrict__ x,
    const float* __restrict__ Wrel, const float* __restrict__ Wroot,
    const float* __restrict__ brel, float* __restrict__ out, int N) {
  __shared__ float sA[ROWS_PER_BLOCK * SA_STRIDE];
  __shared__ float sW[32 * SW_STRIDE];
  const int tid = threadIdx.x;
  const int j0 = (tid & 31) * 4;
  const int r0 = (tid >> 5) * 8;
  const int rowBase = blockIdx.x * ROWS_PER_BLOCK;
  float acc[8][4];
#pragma unroll
  for (int r = 0; r < 8; ++r)
#pragma unroll
    for (int c = 0; c < 4; ++c) acc[r][c] = 0.0f;
  for (int phase = 0; phase < 2; ++phase) {
    const float* __restrict__ A = phase ? x : agg;
    const float* __restrict__ W = phase ? Wroot : Wrel;
    for (int kc = 0; kc < F; kc += 32) {
#pragma unroll
      for (int idx = tid; idx < 512; idx += 256) {
        int row = idx >> 3, k4 = idx & 7;
        float4 v = make_float4(0.f, 0.f, 0.f, 0.f);
        int grow = rowBase + row;
        if (grow < N) v = *(const float4*)&A[(size_t)grow * F + kc + k4 * 4];
        *(float4*)&sA[row * SA_STRIDE + k4 * 4] = v;
      }
#pragma unroll
      for (int idx = tid; idx < 4096; idx += 256) {
        int j = idx >> 5, kk = idx & 31;
        sW[kk * SW_STRIDE + j] = W[j * F + kc + kk];
      }
      __syncthreads();
#pragma unroll
      for (int kk = 0; kk < 32; ++kk) {
        float4 w = *(const float4*)&sW[kk * SW_STRIDE + j0];
#pragma unroll
        for (int r = 0; r < 8; ++r) {
          float a = sA[(r0 + r) * SA_STRIDE + kk];
          acc[r][0] = fmaf(a, w.x, acc[r][0]);
          acc[r][1] = fmaf(a, w.y, acc[r][1]);
          acc[r][2] = fmaf(a, w.z, acc[r][2]);
          acc[r][3] = fmaf(a, w.w, acc[r][3]);
        }
      }
      __syncthreads();
    }
  }
  float b0 = brel[j0], b1 = brel[j0 + 1], b2 = brel[j0 + 2], b3 = brel[j0 + 3];
#pragma unroll
  for (int r = 0; r < 8; ++r) {
    int row = rowBase + r0 + r;
    if (row < N) {
      float4 v;
      v.x = fmaxf(acc[r][0] + b0, 0.0f);
      v.y = fmaxf(acc[r][1] + b1, 0.0f);
      v.z = fmaxf(acc[r][2] + b2, 0.0f);
      v.w = fmaxf(acc[r][3] + b3, 0.0f);
      *(float4*)&out[(size_t)row * F + j0] = v;
    }
  }
}

extern "C" void kernel_launch(void* const* d_in, const int* in_sizes, int n_in,
                              void* d_out, int out_size, void* d_ws, size_t ws_size,
                              hipStream_t stream) {
  const float* x     = (const float*)d_in[0];
  const int*   ei    = (const int*)d_in[1];
  const float* Wrel  = (const float*)d_in[2];
  const float* brel  = (const float*)d_in[3];
  const float* Wroot = (const float*)d_in[4];
  float* out = (float*)d_out;

  const int N = in_sizes[0] / F;   // 50000
  const int E = in_sizes[1] / 2;   // 800000
  const int NB = (N + NPB - 1) / NPB;  // 3125 buckets

  size_t xbBytes  = ((size_t)N * F * 2 + 255) & ~(size_t)255;
  size_t wBytes   = ((size_t)2 * F * F * 2 + 255) & ~(size_t)255;
  size_t curBytes = ((size_t)NPARTS * NB * sizeof(int) + 255) & ~(size_t)255;
  size_t binBytes = ((size_t)NPARTS * NB * CAP * sizeof(unsigned) + 255) & ~(size_t)255;
  size_t needBin  = curBytes + binBytes + xbBytes + wBytes;

  if (ws_size >= needBin) {
    int*      binCursor = (int*)d_ws;
    unsigned* bin = (unsigned*)((char*)d_ws + curBytes);
    unsigned* xb  = (unsigned*)((char*)d_ws + curBytes + binBytes);
    unsigned* wb  = (unsigned*)((char*)d_ws + curBytes + binBytes + xbBytes);

    const int n2x = N * (F / 2);
    const int n2w = F * F / 2;
    hipMemsetAsync(binCursor, 0, (size_t)NPARTS * NB * sizeof(int), stream);
    prep_bin_kernel<<<2048, 256, 0, stream>>>(
        (const float2*)x, (const float2*)Wrel, (const float2*)Wroot, ei, xb, wb,
        binCursor, bin, E, NB, n2x, n2w);
    agg_gemm_kernel<<<NB, 256, 0, stream>>>(xb, bin, binCursor,
                                            (const __bf16*)wb, brel, out, N, NB);
  } else {
    hipMemsetAsync(out, 0, (size_t)N * F * sizeof(float), stream);
    long long total = (long long)E * 32;
    scatter_add_kernel<<<(int)((total + 255) / 256), 256, 0, stream>>>(
        (const float4*)x, ei, out, E);
    gemm_fused_kernel<<<(N + ROWS_PER_BLOCK - 1) / ROWS_PER_BLOCK, 256, 0,
                        stream>>>(out, x, Wrel, Wroot, brel, out, N);
  }
}

// Round 9
// 180.401 us; speedup vs baseline: 1.0256x; 1.0256x over previous
//
#include <hip/hip_runtime.h>
#include <hip/hip_bf16.h>

// GraphConv: out = relu( segment_sum(x[src], dst) @ W_rel^T + b_rel + x @ W_root^T )
// N = 50000, F = 128, E = 800000.
//
// R9: NPB back to 32 (R8's NPB=16 doubled per-block fixed costs: 53.5->67.8us).
// agg_gemm now 512 threads/block (8 waves): 32 resident waves/CU (was 24) with
// unchanged per-block W/sort overhead; gather unrolled 8-deep for MLP.
// Pipeline: memsetAsync(cursors) -> prep_bin -> agg_gemm.  (3 dispatches)

#define F 128
#define NPB 32              // nodes per bucket
#define NPARTS 8            // write partitions (blockIdx%8 ~ XCD heuristic)
#define CAP 128             // slots per (part,bucket); mean 64 -> +8 sigma
#define CAPB 768            // LDS edge slots per bucket; mean 512 -> +11 sigma
#define AST 68              // A-tile row stride in uints (136 bf16; 16B-aligned
                            // rows; stride-4 banks -> 2-way conflicts = free)

typedef __bf16 bf16x8 __attribute__((ext_vector_type(8)));
typedef float f32x4 __attribute__((ext_vector_type(4)));

__device__ inline unsigned f32_to_bf16_rne(float f) {
  unsigned u = __float_as_uint(f);
  unsigned r = u + 0x7fffu + ((u >> 16) & 1u);
  return r >> 16;
}
__device__ inline unsigned pack2(float2 v) {
  return f32_to_bf16_rne(v.x) | (f32_to_bf16_rne(v.y) << 16);
}
__device__ inline void upk(unsigned v, float& ax, float& ay) {
  ax += __uint_as_float(v << 16);
  ay += __uint_as_float(v & 0xffff0000u);
}

// ---------------------------------------------------------------------------
// Kernel 1: fused bf16 convert (x, Wrel, Wroot) + edge binning by dst>>5.
// Cursor array zeroed by hipMemsetAsync before this kernel.
// ---------------------------------------------------------------------------
__global__ __launch_bounds__(256) void prep_bin_kernel(
    const float2* __restrict__ x, const float2* __restrict__ w0,
    const float2* __restrict__ w1, const int* __restrict__ ei,
    unsigned* __restrict__ xb, unsigned* __restrict__ wb,
    int* __restrict__ binCursor, unsigned* __restrict__ bin,
    int E, int NB, int n2x, int n2w) {
  const int tid0 = blockIdx.x * blockDim.x + threadIdx.x;
  const int stride = gridDim.x * blockDim.x;

  const int totalc = n2x + 2 * n2w;
  for (int i = tid0; i < totalc; i += stride) {
    if (i < n2x) {
      xb[i] = pack2(x[i]);
    } else if (i < n2x + n2w) {
      int j = i - n2x;
      wb[j] = pack2(w0[j]);
    } else {
      int j = i - n2x - n2w;
      wb[n2w + j] = pack2(w1[j]);
    }
  }

  const int part = blockIdx.x & (NPARTS - 1);
  for (int e = tid0; e < E; e += stride) {
    unsigned src = (unsigned)ei[e];
    unsigned dst = (unsigned)ei[E + e];
    unsigned key = (dst << 16) | src;
    int cell = part * NB + (int)(dst >> 5);
    int slot = atomicAdd(&binCursor[cell], 1);
    if (slot < CAP) bin[(size_t)cell * CAP + slot] = key;
  }
}

// ---------------------------------------------------------------------------
// Kernel 2: per-bucket LDS counting sort + wave-per-node register gather
//           -> bf16 A-tile in LDS -> fused dual MFMA GEMM + bias + ReLU.
// One block (512 threads, 8 waves) per 32-node bucket; 1563 blocks.
// ---------------------------------------------------------------------------
__global__ __launch_bounds__(512) void agg_gemm_kernel(
    const unsigned* __restrict__ xb, const unsigned* __restrict__ bin,
    const int* __restrict__ binCursor, const __bf16* __restrict__ wb,
    const float* __restrict__ brel, float* __restrict__ out, int N, int NB) {
  __shared__ int cntS[NPB];
  __shared__ int offS[NPB];
  __shared__ int curS[NPB];
  __shared__ unsigned short eLds[CAPB];
  __shared__ unsigned aLds[NPB * AST];  // 32 rows x 128 bf16 (padded)
  const int b = blockIdx.x;
  const int t = threadIdx.x;

  if (t < NPB) cntS[t] = 0;
  __syncthreads();

  // --- stage edges into registers + LDS histogram by local node id
  unsigned kreg[NPARTS];
  int cnt_p[NPARTS];
#pragma unroll
  for (int p = 0; p < NPARTS; ++p) {
    int cell = p * NB + b;
    int c = min(binCursor[cell], CAP);
    cnt_p[p] = c;
    if (t < c) {
      kreg[p] = bin[(size_t)cell * CAP + t];
      atomicAdd(&cntS[(kreg[p] >> 16) & (NPB - 1)], 1);
    }
  }
  __syncthreads();

  // --- exclusive scan of 32 counts (first wave)
  if (t < 64) {
    int v = (t < NPB) ? cntS[t] : 0;
    int incl = v;
#pragma unroll
    for (int off = 1; off < NPB; off <<= 1) {
      int u = __shfl_up(incl, off);
      if (t >= off) incl += u;
    }
    if (t < NPB) {
      offS[t] = incl - v;
      curS[t] = incl - v;
    }
  }
  __syncthreads();

  // --- scatter srcs into LDS, grouped by local node id
#pragma unroll
  for (int p = 0; p < NPARTS; ++p) {
    if (t < cnt_p[p]) {
      int d = (kreg[p] >> 16) & (NPB - 1);
      int pos = atomicAdd(&curS[d], 1);
      if (pos < CAPB) eLds[pos] = (unsigned short)(kreg[p] & 0xffffu);
    }
  }
  __syncthreads();

  // --- wave-per-node gather-accumulate -> bf16 A-tile row in LDS
  const int wave = t >> 6;
  const int lane = t & 63;
  const int nodeBase = b * NPB;
#pragma unroll
  for (int di = wave; di < NPB; di += 8) {
    float ax = 0.f, ay = 0.f;
    int beg = min(offS[di], CAPB);
    int end = min(offS[di] + cntS[di], CAPB);
    int e = beg;
    for (; e + 7 < end; e += 8) {
      int s0 = eLds[e + 0];
      int s1 = eLds[e + 1];
      int s2 = eLds[e + 2];
      int s3 = eLds[e + 3];
      int s4 = eLds[e + 4];
      int s5 = eLds[e + 5];
      int s6 = eLds[e + 6];
      int s7 = eLds[e + 7];
      unsigned v0 = xb[(size_t)s0 * 64 + lane];
      unsigned v1 = xb[(size_t)s1 * 64 + lane];
      unsigned v2 = xb[(size_t)s2 * 64 + lane];
      unsigned v3 = xb[(size_t)s3 * 64 + lane];
      unsigned v4 = xb[(size_t)s4 * 64 + lane];
      unsigned v5 = xb[(size_t)s5 * 64 + lane];
      unsigned v6 = xb[(size_t)s6 * 64 + lane];
      unsigned v7 = xb[(size_t)s7 * 64 + lane];
      upk(v0, ax, ay);
      upk(v1, ax, ay);
      upk(v2, ax, ay);
      upk(v3, ax, ay);
      upk(v4, ax, ay);
      upk(v5, ax, ay);
      upk(v6, ax, ay);
      upk(v7, ax, ay);
    }
    for (; e + 3 < end; e += 4) {
      int s0 = eLds[e + 0];
      int s1 = eLds[e + 1];
      int s2 = eLds[e + 2];
      int s3 = eLds[e + 3];
      unsigned v0 = xb[(size_t)s0 * 64 + lane];
      unsigned v1 = xb[(size_t)s1 * 64 + lane];
      unsigned v2 = xb[(size_t)s2 * 64 + lane];
      unsigned v3 = xb[(size_t)s3 * 64 + lane];
      upk(v0, ax, ay);
      upk(v1, ax, ay);
      upk(v2, ax, ay);
      upk(v3, ax, ay);
    }
    for (; e < end; ++e) upk(xb[(size_t)eLds[e] * 64 + lane], ax, ay);
    aLds[di * AST + lane] = f32_to_bf16_rne(ax) | (f32_to_bf16_rne(ay) << 16);
  }
  __syncthreads();

  // --- fused dual GEMM: M=32 (bucket nodes), Ncols=128, K=128, 2 phases.
  // Wave w owns 16-col group nt = w.
  const int m16 = lane & 15;
  const int quad = lane >> 4;
  const f32x4 zero4 = {0.f, 0.f, 0.f, 0.f};
  const bf16x8 zero8 = {};
  f32x4 acc[2];  // [mt]
  acc[0] = zero4;
  acc[1] = zero4;

#pragma unroll
  for (int ph = 0; ph < 2; ++ph) {
    const __bf16* __restrict__ W = wb + (size_t)ph * F * F;  // 0=Wrel, 1=Wroot
#pragma unroll
    for (int k0 = 0; k0 < F; k0 += 32) {
      const int kcol = k0 + 8 * quad;
      bf16x8 a[2], bw;
#pragma unroll
      for (int mt = 0; mt < 2; ++mt) {
        if (ph == 0) {
          a[mt] = *(const bf16x8*)&aLds[(mt * 16 + m16) * AST + (kcol >> 1)];
        } else {
          int row = nodeBase + mt * 16 + m16;
          a[mt] = (row < N)
                      ? *(const bf16x8*)((const __bf16*)xb + (size_t)row * F + kcol)
                      : zero8;
        }
      }
      bw = *(const bf16x8*)(W + (size_t)(wave * 16 + m16) * F + kcol);
#pragma unroll
      for (int mt = 0; mt < 2; ++mt)
        acc[mt] = __builtin_amdgcn_mfma_f32_16x16x32_bf16(a[mt], bw, acc[mt], 0, 0, 0);
    }
  }

  // --- epilogue: bias + ReLU + store (C/D: col=lane&15, row=quad*4+reg)
  float bias = brel[wave * 16 + m16];
#pragma unroll
  for (int mt = 0; mt < 2; ++mt) {
    int row0 = nodeBase + mt * 16 + quad * 4;
#pragma unroll
    for (int r = 0; r < 4; ++r) {
      int row = row0 + r;
      if (row < N)
        out[(size_t)row * F + wave * 16 + m16] = fmaxf(acc[mt][r] + bias, 0.f);
    }
  }
}

// ===========================================================================
// Fallback (tiny ws): fp32 atomics into out + fused fp32 GEMM in-place
// ===========================================================================
__global__ __launch_bounds__(256) void scatter_add_kernel(
    const float4* __restrict__ x4, const int* __restrict__ ei,
    float* __restrict__ agg, int E) {
  int gid = blockIdx.x * blockDim.x + threadIdx.x;
  if (gid >= E * 32) return;
  int e = gid >> 5, q = gid & 31;
  float4 v = x4[(size_t)ei[e] * 32 + q];
  float* a = agg + (size_t)ei[E + e] * F + q * 4;
  atomicAdd(a + 0, v.x);
  atomicAdd(a + 1, v.y);
  atomicAdd(a + 2, v.z);
  atomicAdd(a + 3, v.w);
}

#define ROWS_PER_BLOCK 64
#define SA_STRIDE 36
#define SW_STRIDE 132

__global__ __launch_bounds__(256) void gemm_fused_kernel(
    const float* __restrict__ agg, const float* __restrict__ x,
    const float* __restrict__ Wrel, const float* __restrict__ Wroot,
    const float* __restrict__ brel, float* __restrict__ out, int N) {
  __shared__ float sA[ROWS_PER_BLOCK * SA_STRIDE];
  __shared__ float sW[32 * SW_STRIDE];
  const int tid = threadIdx.x;
  const int j0 = (tid & 31) * 4;
  const int r0 = (tid >> 5) * 8;
  const int rowBase = blockIdx.x * ROWS_PER_BLOCK;
  float acc[8][4];
#pragma unroll
  for (int r = 0; r < 8; ++r)
#pragma unroll
    for (int c = 0; c < 4; ++c) acc[r][c] = 0.0f;
  for (int phase = 0; phase < 2; ++phase) {
    const float* __restrict__ A = phase ? x : agg;
    const float* __restrict__ W = phase ? Wroot : Wrel;
    for (int kc = 0; kc < F; kc += 32) {
#pragma unroll
      for (int idx = tid; idx < 512; idx += 256) {
        int row = idx >> 3, k4 = idx & 7;
        float4 v = make_float4(0.f, 0.f, 0.f, 0.f);
        int grow = rowBase + row;
        if (grow < N) v = *(const float4*)&A[(size_t)grow * F + kc + k4 * 4];
        *(float4*)&sA[row * SA_STRIDE + k4 * 4] = v;
      }
#pragma unroll
      for (int idx = tid; idx < 4096; idx += 256) {
        int j = idx >> 5, kk = idx & 31;
        sW[kk * SW_STRIDE + j] = W[j * F + kc + kk];
      }
      __syncthreads();
#pragma unroll
      for (int kk = 0; kk < 32; ++kk) {
        float4 w = *(const float4*)&sW[kk * SW_STRIDE + j0];
#pragma unroll
        for (int r = 0; r < 8; ++r) {
          float a = sA[(r0 + r) * SA_STRIDE + kk];
          acc[r][0] = fmaf(a, w.x, acc[r][0]);
          acc[r][1] = fmaf(a, w.y, acc[r][1]);
          acc[r][2] = fmaf(a, w.z, acc[r][2]);
          acc[r][3] = fmaf(a, w.w, acc[r][3]);
        }
      }
      __syncthreads();
    }
  }
  float b0 = brel[j0], b1 = brel[j0 + 1], b2 = brel[j0 + 2], b3 = brel[j0 + 3];
#pragma unroll
  for (int r = 0; r < 8; ++r) {
    int row = rowBase + r0 + r;
    if (row < N) {
      float4 v;
      v.x = fmaxf(acc[r][0] + b0, 0.0f);
      v.y = fmaxf(acc[r][1] + b1, 0.0f);
      v.z = fmaxf(acc[r][2] + b2, 0.0f);
      v.w = fmaxf(acc[r][3] + b3, 0.0f);
      *(float4*)&out[(size_t)row * F + j0] = v;
    }
  }
}

extern "C" void kernel_launch(void* const* d_in, const int* in_sizes, int n_in,
                              void* d_out, int out_size, void* d_ws, size_t ws_size,
                              hipStream_t stream) {
  const float* x     = (const float*)d_in[0];
  const int*   ei    = (const int*)d_in[1];
  const float* Wrel  = (const float*)d_in[2];
  const float* brel  = (const float*)d_in[3];
  const float* Wroot = (const float*)d_in[4];
  float* out = (float*)d_out;

  const int N = in_sizes[0] / F;   // 50000
  const int E = in_sizes[1] / 2;   // 800000
  const int NB = (N + NPB - 1) / NPB;  // 1563 buckets

  size_t xbBytes  = ((size_t)N * F * 2 + 255) & ~(size_t)255;
  size_t wBytes   = ((size_t)2 * F * F * 2 + 255) & ~(size_t)255;
  size_t curBytes = ((size_t)NPARTS * NB * sizeof(int) + 255) & ~(size_t)255;
  size_t binBytes = ((size_t)NPARTS * NB * CAP * sizeof(unsigned) + 255) & ~(size_t)255;
  size_t needBin  = curBytes + binBytes + xbBytes + wBytes;

  if (ws_size >= needBin) {
    int*      binCursor = (int*)d_ws;
    unsigned* bin = (unsigned*)((char*)d_ws + curBytes);
    unsigned* xb  = (unsigned*)((char*)d_ws + curBytes + binBytes);
    unsigned* wb  = (unsigned*)((char*)d_ws + curBytes + binBytes + xbBytes);

    const int n2x = N * (F / 2);
    const int n2w = F * F / 2;
    hipMemsetAsync(binCursor, 0, (size_t)NPARTS * NB * sizeof(int), stream);
    prep_bin_kernel<<<2048, 256, 0, stream>>>(
        (const float2*)x, (const float2*)Wrel, (const float2*)Wroot, ei, xb, wb,
        binCursor, bin, E, NB, n2x, n2w);
    agg_gemm_kernel<<<NB, 512, 0, stream>>>(xb, bin, binCursor,
                                            (const __bf16*)wb, brel, out, N, NB);
  } else {
    hipMemsetAsync(out, 0, (size_t)N * F * sizeof(float), stream);
    long long total = (long long)E * 32;
    scatter_add_kernel<<<(int)((total + 255) / 256), 256, 0, stream>>>(
        (const float4*)x, ei, out, E);
    gemm_fused_kernel<<<(N + ROWS_PER_BLOCK - 1) / ROWS_PER_BLOCK, 256, 0,
                        stream>>>(out, x, Wrel, Wroot, brel, out, N);
  }
}

// Round 10
// 169.318 us; speedup vs baseline: 1.0928x; 1.0655x over previous
//
#include <hip/hip_runtime.h>
#include <hip/hip_bf16.h>
#include <hip/hip_cooperative_groups.h>

namespace cg = cooperative_groups;

// GraphConv: out = relu( segment_sum(x[src], dst) @ W_rel^T + b_rel + x @ W_root^T )
// N = 50000, F = 128, E = 800000.
//
// R10: single cooperative kernel (1563 blocks x 256 thr, 8 blocks/CU capacity):
//   A: zero cursors + bf16 converts -> grid.sync
//   B: bin edges (dst>>5 buckets, XCD-partitioned regions) -> grid.sync
//   C: per-bucket LDS sort + wave-per-node gather + dual MFMA GEMM (R7 body,
//      proven 53.5us). Removes 3 launches + 2 full inter-kernel drains.
// Fallback: proven R7 3-dispatch path, then fp32 path.

#define F 128
#define NPB 32              // nodes per bucket
#define NPARTS 8            // write partitions (blockIdx%8 ~ XCD heuristic)
#define CAP 128             // slots per (part,bucket); mean 64 -> +8 sigma
#define CAPB 768            // LDS edge slots per bucket; mean 512 -> +11 sigma
#define AST 68              // A-tile row stride in uints

typedef __bf16 bf16x8 __attribute__((ext_vector_type(8)));
typedef float f32x4 __attribute__((ext_vector_type(4)));

__device__ inline unsigned f32_to_bf16_rne(float f) {
  unsigned u = __float_as_uint(f);
  unsigned r = u + 0x7fffu + ((u >> 16) & 1u);
  return r >> 16;
}
__device__ inline unsigned pack2(float2 v) {
  return f32_to_bf16_rne(v.x) | (f32_to_bf16_rne(v.y) << 16);
}
__device__ inline void upk(unsigned v, float& ax, float& ay) {
  ax += __uint_as_float(v << 16);
  ay += __uint_as_float(v & 0xffff0000u);
}

// ---------------------------------------------------------------------------
// The whole pipeline as one cooperative kernel.
// ---------------------------------------------------------------------------
__global__ __launch_bounds__(256) void mega_kernel(
    const float2* __restrict__ x, const float2* __restrict__ w0,
    const float2* __restrict__ w1, const int* __restrict__ ei,
    unsigned* __restrict__ xb, unsigned* __restrict__ wb,
    int* __restrict__ binCursor, unsigned* __restrict__ bin,
    const float* __restrict__ brel, float* __restrict__ out,
    int N, int E, int NB, int n2x, int n2w) {
  cg::grid_group grid = cg::this_grid();
  const int t = threadIdx.x;
  const int b = blockIdx.x;
  const int gtid = b * 256 + t;
  const int gstride = gridDim.x * 256;

  // ---- Phase A: zero bin cursors + bf16 converts ----
  for (int i = gtid; i < NPARTS * NB; i += gstride) binCursor[i] = 0;
  for (int i = gtid; i < n2x; i += gstride) xb[i] = pack2(x[i]);
  for (int i = gtid; i < 2 * n2w; i += gstride)
    wb[i] = (i < n2w) ? pack2(w0[i]) : pack2(w1[i - n2w]);
  grid.sync();

  // ---- Phase B: bin edges by dst>>5, partitioned by blockIdx%8 ----
  const int part = b & (NPARTS - 1);
  for (int e = gtid; e < E; e += gstride) {
    unsigned src = (unsigned)ei[e];
    unsigned dst = (unsigned)ei[E + e];
    int cell = part * NB + (int)(dst >> 5);
    int slot = atomicAdd(&binCursor[cell], 1);
    if (slot < CAP) bin[(size_t)cell * CAP + slot] = (dst << 16) | src;
  }
  grid.sync();

  // ---- Phase C: per-bucket LDS sort + gather + fused dual MFMA GEMM ----
  __shared__ int cntS[NPB];
  __shared__ int offS[NPB];
  __shared__ int curS[NPB];
  __shared__ unsigned short eLds[CAPB];
  __shared__ unsigned aLds[NPB * AST];

  if (t < NPB) cntS[t] = 0;
  __syncthreads();

  unsigned kreg[NPARTS];
  int cnt_p[NPARTS];
#pragma unroll
  for (int p = 0; p < NPARTS; ++p) {
    int cell = p * NB + b;
    int c = min(binCursor[cell], CAP);
    cnt_p[p] = c;
    if (t < c) {
      kreg[p] = bin[(size_t)cell * CAP + t];
      atomicAdd(&cntS[(kreg[p] >> 16) & (NPB - 1)], 1);
    }
  }
  __syncthreads();

  if (t < 64) {
    int v = (t < NPB) ? cntS[t] : 0;
    int incl = v;
#pragma unroll
    for (int off = 1; off < NPB; off <<= 1) {
      int u = __shfl_up(incl, off);
      if (t >= off) incl += u;
    }
    if (t < NPB) {
      offS[t] = incl - v;
      curS[t] = incl - v;
    }
  }
  __syncthreads();

#pragma unroll
  for (int p = 0; p < NPARTS; ++p) {
    if (t < cnt_p[p]) {
      int d = (kreg[p] >> 16) & (NPB - 1);
      int pos = atomicAdd(&curS[d], 1);
      if (pos < CAPB) eLds[pos] = (unsigned short)(kreg[p] & 0xffffu);
    }
  }
  __syncthreads();

  const int wave = t >> 6;
  const int lane = t & 63;
  const int nodeBase = b * NPB;
#pragma unroll
  for (int di = wave; di < NPB; di += 4) {
    float ax = 0.f, ay = 0.f;
    int beg = min(offS[di], CAPB);
    int end = min(offS[di] + cntS[di], CAPB);
    int e = beg;
    for (; e + 3 < end; e += 4) {
      int s0 = eLds[e + 0];
      int s1 = eLds[e + 1];
      int s2 = eLds[e + 2];
      int s3 = eLds[e + 3];
      unsigned v0 = xb[(size_t)s0 * 64 + lane];
      unsigned v1 = xb[(size_t)s1 * 64 + lane];
      unsigned v2 = xb[(size_t)s2 * 64 + lane];
      unsigned v3 = xb[(size_t)s3 * 64 + lane];
      upk(v0, ax, ay);
      upk(v1, ax, ay);
      upk(v2, ax, ay);
      upk(v3, ax, ay);
    }
    for (; e < end; ++e) upk(xb[(size_t)eLds[e] * 64 + lane], ax, ay);
    aLds[di * AST + lane] = f32_to_bf16_rne(ax) | (f32_to_bf16_rne(ay) << 16);
  }
  __syncthreads();

  // Dual GEMM: M=32, Ncols=128, K=128, 2 phases; wave owns nt = 2*wave+s.
  const int m16 = lane & 15;
  const int quad = lane >> 4;
  const f32x4 zero4 = {0.f, 0.f, 0.f, 0.f};
  const bf16x8 zero8 = {};
  f32x4 acc[2][2];
#pragma unroll
  for (int mt = 0; mt < 2; ++mt)
#pragma unroll
    for (int s = 0; s < 2; ++s) acc[mt][s] = zero4;

  const __bf16* __restrict__ wbb = (const __bf16*)wb;
#pragma unroll
  for (int ph = 0; ph < 2; ++ph) {
    const __bf16* __restrict__ W = wbb + (size_t)ph * F * F;
#pragma unroll
    for (int k0 = 0; k0 < F; k0 += 32) {
      const int kcol = k0 + 8 * quad;
      bf16x8 a[2], bw[2];
#pragma unroll
      for (int mt = 0; mt < 2; ++mt) {
        if (ph == 0) {
          a[mt] = *(const bf16x8*)&aLds[(mt * 16 + m16) * AST + (kcol >> 1)];
        } else {
          int row = nodeBase + mt * 16 + m16;
          a[mt] = (row < N)
                      ? *(const bf16x8*)((const __bf16*)xb + (size_t)row * F + kcol)
                      : zero8;
        }
      }
#pragma unroll
      for (int s = 0; s < 2; ++s) {
        int nt = wave * 2 + s;
        bw[s] = *(const bf16x8*)(W + (size_t)(nt * 16 + m16) * F + kcol);
      }
#pragma unroll
      for (int mt = 0; mt < 2; ++mt)
#pragma unroll
        for (int s = 0; s < 2; ++s)
          acc[mt][s] = __builtin_amdgcn_mfma_f32_16x16x32_bf16(
              a[mt], bw[s], acc[mt][s], 0, 0, 0);
    }
  }

#pragma unroll
  for (int s = 0; s < 2; ++s) {
    int nt = wave * 2 + s;
    float bias = brel[nt * 16 + m16];
#pragma unroll
    for (int mt = 0; mt < 2; ++mt) {
      int row0 = nodeBase + mt * 16 + quad * 4;
#pragma unroll
      for (int r = 0; r < 4; ++r) {
        int row = row0 + r;
        if (row < N)
          out[(size_t)row * F + nt * 16 + m16] = fmaxf(acc[mt][s][r] + bias, 0.f);
      }
    }
  }
}

// ===========================================================================
// Fallback A: proven R7 3-dispatch path (memset -> prep_bin -> agg_gemm)
// ===========================================================================
__global__ __launch_bounds__(256) void prep_bin_kernel(
    const float2* __restrict__ x, const float2* __restrict__ w0,
    const float2* __restrict__ w1, const int* __restrict__ ei,
    unsigned* __restrict__ xb, unsigned* __restrict__ wb,
    int* __restrict__ binCursor, unsigned* __restrict__ bin,
    int E, int NB, int n2x, int n2w) {
  const int tid0 = blockIdx.x * blockDim.x + threadIdx.x;
  const int stride = gridDim.x * blockDim.x;
  const int totalc = n2x + 2 * n2w;
  for (int i = tid0; i < totalc; i += stride) {
    if (i < n2x) xb[i] = pack2(x[i]);
    else if (i < n2x + n2w) wb[i - n2x] = pack2(w0[i - n2x]);
    else wb[i - n2x] = pack2(w1[i - n2x - n2w]);
  }
  const int part = blockIdx.x & (NPARTS - 1);
  for (int e = tid0; e < E; e += stride) {
    unsigned src = (unsigned)ei[e];
    unsigned dst = (unsigned)ei[E + e];
    int cell = part * NB + (int)(dst >> 5);
    int slot = atomicAdd(&binCursor[cell], 1);
    if (slot < CAP) bin[(size_t)cell * CAP + slot] = (dst << 16) | src;
  }
}

__global__ __launch_bounds__(256) void agg_gemm_kernel(
    const unsigned* __restrict__ xb, const unsigned* __restrict__ bin,
    const int* __restrict__ binCursor, const __bf16* __restrict__ wb,
    const float* __restrict__ brel, float* __restrict__ out, int N, int NB) {
  __shared__ int cntS[NPB];
  __shared__ int offS[NPB];
  __shared__ int curS[NPB];
  __shared__ unsigned short eLds[CAPB];
  __shared__ unsigned aLds[NPB * AST];
  const int b = blockIdx.x;
  const int t = threadIdx.x;
  if (t < NPB) cntS[t] = 0;
  __syncthreads();
  unsigned kreg[NPARTS];
  int cnt_p[NPARTS];
#pragma unroll
  for (int p = 0; p < NPARTS; ++p) {
    int cell = p * NB + b;
    int c = min(binCursor[cell], CAP);
    cnt_p[p] = c;
    if (t < c) {
      kreg[p] = bin[(size_t)cell * CAP + t];
      atomicAdd(&cntS[(kreg[p] >> 16) & (NPB - 1)], 1);
    }
  }
  __syncthreads();
  if (t < 64) {
    int v = (t < NPB) ? cntS[t] : 0;
    int incl = v;
#pragma unroll
    for (int off = 1; off < NPB; off <<= 1) {
      int u = __shfl_up(incl, off);
      if (t >= off) incl += u;
    }
    if (t < NPB) {
      offS[t] = incl - v;
      curS[t] = incl - v;
    }
  }
  __syncthreads();
#pragma unroll
  for (int p = 0; p < NPARTS; ++p) {
    if (t < cnt_p[p]) {
      int d = (kreg[p] >> 16) & (NPB - 1);
      int pos = atomicAdd(&curS[d], 1);
      if (pos < CAPB) eLds[pos] = (unsigned short)(kreg[p] & 0xffffu);
    }
  }
  __syncthreads();
  const int wave = t >> 6;
  const int lane = t & 63;
  const int nodeBase = b * NPB;
#pragma unroll
  for (int di = wave; di < NPB; di += 4) {
    float ax = 0.f, ay = 0.f;
    int beg = min(offS[di], CAPB);
    int end = min(offS[di] + cntS[di], CAPB);
    int e = beg;
    for (; e + 3 < end; e += 4) {
      int s0 = eLds[e + 0];
      int s1 = eLds[e + 1];
      int s2 = eLds[e + 2];
      int s3 = eLds[e + 3];
      unsigned v0 = xb[(size_t)s0 * 64 + lane];
      unsigned v1 = xb[(size_t)s1 * 64 + lane];
      unsigned v2 = xb[(size_t)s2 * 64 + lane];
      unsigned v3 = xb[(size_t)s3 * 64 + lane];
      upk(v0, ax, ay);
      upk(v1, ax, ay);
      upk(v2, ax, ay);
      upk(v3, ax, ay);
    }
    for (; e < end; ++e) upk(xb[(size_t)eLds[e] * 64 + lane], ax, ay);
    aLds[di * AST + lane] = f32_to_bf16_rne(ax) | (f32_to_bf16_rne(ay) << 16);
  }
  __syncthreads();
  const int m16 = lane & 15;
  const int quad = lane >> 4;
  const f32x4 zero4 = {0.f, 0.f, 0.f, 0.f};
  const bf16x8 zero8 = {};
  f32x4 acc[2][2];
#pragma unroll
  for (int mt = 0; mt < 2; ++mt)
#pragma unroll
    for (int s = 0; s < 2; ++s) acc[mt][s] = zero4;
#pragma unroll
  for (int ph = 0; ph < 2; ++ph) {
    const __bf16* __restrict__ W = wb + (size_t)ph * F * F;
#pragma unroll
    for (int k0 = 0; k0 < F; k0 += 32) {
      const int kcol = k0 + 8 * quad;
      bf16x8 a[2], bw[2];
#pragma unroll
      for (int mt = 0; mt < 2; ++mt) {
        if (ph == 0) {
          a[mt] = *(const bf16x8*)&aLds[(mt * 16 + m16) * AST + (kcol >> 1)];
        } else {
          int row = nodeBase + mt * 16 + m16;
          a[mt] = (row < N)
                      ? *(const bf16x8*)((const __bf16*)xb + (size_t)row * F + kcol)
                      : zero8;
        }
      }
#pragma unroll
      for (int s = 0; s < 2; ++s) {
        int nt = wave * 2 + s;
        bw[s] = *(const bf16x8*)(W + (size_t)(nt * 16 + m16) * F + kcol);
      }
#pragma unroll
      for (int mt = 0; mt < 2; ++mt)
#pragma unroll
        for (int s = 0; s < 2; ++s)
          acc[mt][s] = __builtin_amdgcn_mfma_f32_16x16x32_bf16(
              a[mt], bw[s], acc[mt][s], 0, 0, 0);
    }
  }
#pragma unroll
  for (int s = 0; s < 2; ++s) {
    int nt = wave * 2 + s;
    float bias = brel[nt * 16 + m16];
#pragma unroll
    for (int mt = 0; mt < 2; ++mt) {
      int row0 = nodeBase + mt * 16 + quad * 4;
#pragma unroll
      for (int r = 0; r < 4; ++r) {
        int row = row0 + r;
        if (row < N)
          out[(size_t)row * F + nt * 16 + m16] = fmaxf(acc[mt][s][r] + bias, 0.f);
      }
    }
  }
}

// ===========================================================================
// Fallback B (tiny ws): fp32 atomics into out + fused fp32 GEMM in-place
// ===========================================================================
__global__ __launch_bounds__(256) void scatter_add_kernel(
    const float4* __restrict__ x4, const int* __restrict__ ei,
    float* __restrict__ agg, int E) {
  int gid = blockIdx.x * blockDim.x + threadIdx.x;
  if (gid >= E * 32) return;
  int e = gid >> 5, q = gid & 31;
  float4 v = x4[(size_t)ei[e] * 32 + q];
  float* a = agg + (size_t)ei[E + e] * F + q * 4;
  atomicAdd(a + 0, v.x);
  atomicAdd(a + 1, v.y);
  atomicAdd(a + 2, v.z);
  atomicAdd(a + 3, v.w);
}

#define ROWS_PER_BLOCK 64
#define SA_STRIDE 36
#define SW_STRIDE 132

__global__ __launch_bounds__(256) void gemm_fused_kernel(
    const float* __restrict__ agg, const float* __restrict__ x,
    const float* __restrict__ Wrel, const float* __restrict__ Wroot,
    const float* __restrict__ brel, float* __restrict__ out, int N) {
  __shared__ float sA[ROWS_PER_BLOCK * SA_STRIDE];
  __shared__ float sW[32 * SW_STRIDE];
  const int tid = threadIdx.x;
  const int j0 = (tid & 31) * 4;
  const int r0 = (tid >> 5) * 8;
  const int rowBase = blockIdx.x * ROWS_PER_BLOCK;
  float acc[8][4];
#pragma unroll
  for (int r = 0; r < 8; ++r)
#pragma unroll
    for (int c = 0; c < 4; ++c) acc[r][c] = 0.0f;
  for (int phase = 0; phase < 2; ++phase) {
    const float* __restrict__ A = phase ? x : agg;
    const float* __restrict__ W = phase ? Wroot : Wrel;
    for (int kc = 0; kc < F; kc += 32) {
#pragma unroll
      for (int idx = tid; idx < 512; idx += 256) {
        int row = idx >> 3, k4 = idx & 7;
        float4 v = make_float4(0.f, 0.f, 0.f, 0.f);
        int grow = rowBase + row;
        if (grow < N) v = *(const float4*)&A[(size_t)grow * F + kc + k4 * 4];
        *(float4*)&sA[row * SA_STRIDE + k4 * 4] = v;
      }
#pragma unroll
      for (int idx = tid; idx < 4096; idx += 256) {
        int j = idx >> 5, kk = idx & 31;
        sW[kk * SW_STRIDE + j] = W[j * F + kc + kk];
      }
      __syncthreads();
#pragma unroll
      for (int kk = 0; kk < 32; ++kk) {
        float4 w = *(const float4*)&sW[kk * SW_STRIDE + j0];
#pragma unroll
        for (int r = 0; r < 8; ++r) {
          float a = sA[(r0 + r) * SA_STRIDE + kk];
          acc[r][0] = fmaf(a, w.x, acc[r][0]);
          acc[r][1] = fmaf(a, w.y, acc[r][1]);
          acc[r][2] = fmaf(a, w.z, acc[r][2]);
          acc[r][3] = fmaf(a, w.w, acc[r][3]);
        }
      }
      __syncthreads();
    }
  }
  float b0 = brel[j0], b1 = brel[j0 + 1], b2 = brel[j0 + 2], b3 = brel[j0 + 3];
#pragma unroll
  for (int r = 0; r < 8; ++r) {
    int row = rowBase + r0 + r;
    if (row < N) {
      float4 v;
      v.x = fmaxf(acc[r][0] + b0, 0.0f);
      v.y = fmaxf(acc[r][1] + b1, 0.0f);
      v.z = fmaxf(acc[r][2] + b2, 0.0f);
      v.w = fmaxf(acc[r][3] + b3, 0.0f);
      *(float4*)&out[(size_t)row * F + j0] = v;
    }
  }
}

extern "C" void kernel_launch(void* const* d_in, const int* in_sizes, int n_in,
                              void* d_out, int out_size, void* d_ws, size_t ws_size,
                              hipStream_t stream) {
  const float* x     = (const float*)d_in[0];
  const int*   ei    = (const int*)d_in[1];
  const float* Wrel  = (const float*)d_in[2];
  const float* brel  = (const float*)d_in[3];
  const float* Wroot = (const float*)d_in[4];
  float* out = (float*)d_out;

  const int N = in_sizes[0] / F;       // 50000
  const int E = in_sizes[1] / 2;       // 800000
  const int NB = (N + NPB - 1) / NPB;  // 1563 buckets

  size_t xbBytes  = ((size_t)N * F * 2 + 255) & ~(size_t)255;
  size_t wBytes   = ((size_t)2 * F * F * 2 + 255) & ~(size_t)255;
  size_t curBytes = ((size_t)NPARTS * NB * sizeof(int) + 255) & ~(size_t)255;
  size_t binBytes = ((size_t)NPARTS * NB * CAP * sizeof(unsigned) + 255) & ~(size_t)255;
  size_t needBin  = curBytes + binBytes + xbBytes + wBytes;

  if (ws_size >= needBin) {
    int*      binCursor = (int*)d_ws;
    unsigned* bin = (unsigned*)((char*)d_ws + curBytes);
    unsigned* xb  = (unsigned*)((char*)d_ws + curBytes + binBytes);
    unsigned* wb  = (unsigned*)((char*)d_ws + curBytes + binBytes + xbBytes);

    int n2x = N * (F / 2);
    int n2w = F * F / 2;

    // Co-residency check for the cooperative launch (host-side query only).
    int maxBlocksPerCU = 0;
    hipError_t qerr = hipOccupancyMaxActiveBlocksPerMultiprocessor(
        &maxBlocksPerCU, (const void*)mega_kernel, 256, 0);
    bool coopOk = (qerr == hipSuccess) && (maxBlocksPerCU * 256 >= NB);

    if (coopOk) {
      const float2* xa = (const float2*)x;
      const float2* w0 = (const float2*)Wrel;
      const float2* w1 = (const float2*)Wroot;
      void* args[] = {(void*)&xa, (void*)&w0, (void*)&w1, (void*)&ei,
                      (void*)&xb, (void*)&wb, (void*)&binCursor, (void*)&bin,
                      (void*)&brel, (void*)&out,
                      (void*)&N, (void*)&E, (void*)&NB, (void*)&n2x, (void*)&n2w};
      hipError_t lerr = hipLaunchCooperativeKernel(
          (const void*)mega_kernel, dim3(NB), dim3(256), args, 0, stream);
      if (lerr == hipSuccess) return;
      // fall through to classic path if the cooperative launch was rejected
    }

    // --- classic 3-dispatch path (proven R7) ---
    hipMemsetAsync(binCursor, 0, (size_t)NPARTS * NB * sizeof(int), stream);
    prep_bin_kernel<<<2048, 256, 0, stream>>>(
        (const float2*)x, (const float2*)Wrel, (const float2*)Wroot, ei, xb, wb,
        binCursor, bin, E, NB, n2x, n2w);
    agg_gemm_kernel<<<NB, 256, 0, stream>>>(xb, bin, binCursor,
                                            (const __bf16*)wb, brel, out, N, NB);
  } else {
    hipMemsetAsync(out, 0, (size_t)N * F * sizeof(float), stream);
    long long total = (long long)E * 32;
    scatter_add_kernel<<<(int)((total + 255) / 256), 256, 0, stream>>>(
        (const float4*)x, ei, out, E);
    gemm_fused_kernel<<<(N + ROWS_PER_BLOCK - 1) / ROWS_PER_BLOCK, 256, 0,
                        stream>>>(out, x, Wrel, Wroot, brel, out, N);
  }
}

// Round 11
// 168.539 us; speedup vs baseline: 1.0978x; 1.0046x over previous
//
#include <hip/hip_runtime.h>
#include <hip/hip_bf16.h>
#include <hip/hip_cooperative_groups.h>

namespace cg = cooperative_groups;

// GraphConv: out = relu( segment_sum(x[src], dst) @ W_rel^T + b_rel + x @ W_root^T )
// N = 50000, F = 128, E = 800000.
//
// R11: R10's single cooperative kernel + ILP tuning in phase C:
//   - staging: issue all 8 partition bin-reads before any LDS histogram atomic
//     (8 independent loads in flight vs 8 dependent round-trips)
//   - gather: 8-deep unroll (at the proven 256-thr/NPB=32 shape)
// Fallback: proven R7 3-dispatch path, then fp32 path.

#define F 128
#define NPB 32              // nodes per bucket
#define NPARTS 8            // write partitions (blockIdx%8 ~ XCD heuristic)
#define CAP 128             // slots per (part,bucket); mean 64 -> +8 sigma
#define CAPB 768            // LDS edge slots per bucket; mean 512 -> +11 sigma
#define AST 68              // A-tile row stride in uints

typedef __bf16 bf16x8 __attribute__((ext_vector_type(8)));
typedef float f32x4 __attribute__((ext_vector_type(4)));

__device__ inline unsigned f32_to_bf16_rne(float f) {
  unsigned u = __float_as_uint(f);
  unsigned r = u + 0x7fffu + ((u >> 16) & 1u);
  return r >> 16;
}
__device__ inline unsigned pack2(float2 v) {
  return f32_to_bf16_rne(v.x) | (f32_to_bf16_rne(v.y) << 16);
}
__device__ inline void upk(unsigned v, float& ax, float& ay) {
  ax += __uint_as_float(v << 16);
  ay += __uint_as_float(v & 0xffff0000u);
}

// ---------------------------------------------------------------------------
// The whole pipeline as one cooperative kernel.
// ---------------------------------------------------------------------------
__global__ __launch_bounds__(256) void mega_kernel(
    const float2* __restrict__ x, const float2* __restrict__ w0,
    const float2* __restrict__ w1, const int* __restrict__ ei,
    unsigned* __restrict__ xb, unsigned* __restrict__ wb,
    int* __restrict__ binCursor, unsigned* __restrict__ bin,
    const float* __restrict__ brel, float* __restrict__ out,
    int N, int E, int NB, int n2x, int n2w) {
  cg::grid_group grid = cg::this_grid();
  const int t = threadIdx.x;
  const int b = blockIdx.x;
  const int gtid = b * 256 + t;
  const int gstride = gridDim.x * 256;

  // ---- Phase A: zero bin cursors + bf16 converts ----
  for (int i = gtid; i < NPARTS * NB; i += gstride) binCursor[i] = 0;
  for (int i = gtid; i < n2x; i += gstride) xb[i] = pack2(x[i]);
  for (int i = gtid; i < 2 * n2w; i += gstride)
    wb[i] = (i < n2w) ? pack2(w0[i]) : pack2(w1[i - n2w]);
  grid.sync();

  // ---- Phase B: bin edges by dst>>5, partitioned by blockIdx%8 ----
  const int part = b & (NPARTS - 1);
  for (int e = gtid; e < E; e += gstride) {
    unsigned src = (unsigned)ei[e];
    unsigned dst = (unsigned)ei[E + e];
    int cell = part * NB + (int)(dst >> 5);
    int slot = atomicAdd(&binCursor[cell], 1);
    if (slot < CAP) bin[(size_t)cell * CAP + slot] = (dst << 16) | src;
  }
  grid.sync();

  // ---- Phase C: per-bucket LDS sort + gather + fused dual MFMA GEMM ----
  __shared__ int cntS[NPB];
  __shared__ int offS[NPB];
  __shared__ int curS[NPB];
  __shared__ unsigned short eLds[CAPB];
  __shared__ unsigned aLds[NPB * AST];

  if (t < NPB) cntS[t] = 0;
  __syncthreads();

  // stage: issue ALL partition loads first (independent), then histogram
  unsigned kreg[NPARTS];
  int cnt_p[NPARTS];
#pragma unroll
  for (int p = 0; p < NPARTS; ++p) {
    int cell = p * NB + b;
    int c = min(binCursor[cell], CAP);
    cnt_p[p] = c;
    kreg[p] = (t < c) ? bin[(size_t)cell * CAP + t] : 0u;
  }
#pragma unroll
  for (int p = 0; p < NPARTS; ++p) {
    if (t < cnt_p[p]) atomicAdd(&cntS[(kreg[p] >> 16) & (NPB - 1)], 1);
  }
  __syncthreads();

  if (t < 64) {
    int v = (t < NPB) ? cntS[t] : 0;
    int incl = v;
#pragma unroll
    for (int off = 1; off < NPB; off <<= 1) {
      int u = __shfl_up(incl, off);
      if (t >= off) incl += u;
    }
    if (t < NPB) {
      offS[t] = incl - v;
      curS[t] = incl - v;
    }
  }
  __syncthreads();

#pragma unroll
  for (int p = 0; p < NPARTS; ++p) {
    if (t < cnt_p[p]) {
      int d = (kreg[p] >> 16) & (NPB - 1);
      int pos = atomicAdd(&curS[d], 1);
      if (pos < CAPB) eLds[pos] = (unsigned short)(kreg[p] & 0xffffu);
    }
  }
  __syncthreads();

  const int wave = t >> 6;
  const int lane = t & 63;
  const int nodeBase = b * NPB;
#pragma unroll
  for (int di = wave; di < NPB; di += 4) {
    float ax = 0.f, ay = 0.f;
    int beg = min(offS[di], CAPB);
    int end = min(offS[di] + cntS[di], CAPB);
    int e = beg;
    for (; e + 7 < end; e += 8) {
      int s0 = eLds[e + 0];
      int s1 = eLds[e + 1];
      int s2 = eLds[e + 2];
      int s3 = eLds[e + 3];
      int s4 = eLds[e + 4];
      int s5 = eLds[e + 5];
      int s6 = eLds[e + 6];
      int s7 = eLds[e + 7];
      unsigned v0 = xb[(size_t)s0 * 64 + lane];
      unsigned v1 = xb[(size_t)s1 * 64 + lane];
      unsigned v2 = xb[(size_t)s2 * 64 + lane];
      unsigned v3 = xb[(size_t)s3 * 64 + lane];
      unsigned v4 = xb[(size_t)s4 * 64 + lane];
      unsigned v5 = xb[(size_t)s5 * 64 + lane];
      unsigned v6 = xb[(size_t)s6 * 64 + lane];
      unsigned v7 = xb[(size_t)s7 * 64 + lane];
      upk(v0, ax, ay);
      upk(v1, ax, ay);
      upk(v2, ax, ay);
      upk(v3, ax, ay);
      upk(v4, ax, ay);
      upk(v5, ax, ay);
      upk(v6, ax, ay);
      upk(v7, ax, ay);
    }
    for (; e + 3 < end; e += 4) {
      int s0 = eLds[e + 0];
      int s1 = eLds[e + 1];
      int s2 = eLds[e + 2];
      int s3 = eLds[e + 3];
      unsigned v0 = xb[(size_t)s0 * 64 + lane];
      unsigned v1 = xb[(size_t)s1 * 64 + lane];
      unsigned v2 = xb[(size_t)s2 * 64 + lane];
      unsigned v3 = xb[(size_t)s3 * 64 + lane];
      upk(v0, ax, ay);
      upk(v1, ax, ay);
      upk(v2, ax, ay);
      upk(v3, ax, ay);
    }
    for (; e < end; ++e) upk(xb[(size_t)eLds[e] * 64 + lane], ax, ay);
    aLds[di * AST + lane] = f32_to_bf16_rne(ax) | (f32_to_bf16_rne(ay) << 16);
  }
  __syncthreads();

  // Dual GEMM: M=32, Ncols=128, K=128, 2 phases; wave owns nt = 2*wave+s.
  const int m16 = lane & 15;
  const int quad = lane >> 4;
  const f32x4 zero4 = {0.f, 0.f, 0.f, 0.f};
  const bf16x8 zero8 = {};
  f32x4 acc[2][2];
#pragma unroll
  for (int mt = 0; mt < 2; ++mt)
#pragma unroll
    for (int s = 0; s < 2; ++s) acc[mt][s] = zero4;

  const __bf16* __restrict__ wbb = (const __bf16*)wb;
#pragma unroll
  for (int ph = 0; ph < 2; ++ph) {
    const __bf16* __restrict__ W = wbb + (size_t)ph * F * F;
#pragma unroll
    for (int k0 = 0; k0 < F; k0 += 32) {
      const int kcol = k0 + 8 * quad;
      bf16x8 a[2], bw[2];
#pragma unroll
      for (int mt = 0; mt < 2; ++mt) {
        if (ph == 0) {
          a[mt] = *(const bf16x8*)&aLds[(mt * 16 + m16) * AST + (kcol >> 1)];
        } else {
          int row = nodeBase + mt * 16 + m16;
          a[mt] = (row < N)
                      ? *(const bf16x8*)((const __bf16*)xb + (size_t)row * F + kcol)
                      : zero8;
        }
      }
#pragma unroll
      for (int s = 0; s < 2; ++s) {
        int nt = wave * 2 + s;
        bw[s] = *(const bf16x8*)(W + (size_t)(nt * 16 + m16) * F + kcol);
      }
#pragma unroll
      for (int mt = 0; mt < 2; ++mt)
#pragma unroll
        for (int s = 0; s < 2; ++s)
          acc[mt][s] = __builtin_amdgcn_mfma_f32_16x16x32_bf16(
              a[mt], bw[s], acc[mt][s], 0, 0, 0);
    }
  }

#pragma unroll
  for (int s = 0; s < 2; ++s) {
    int nt = wave * 2 + s;
    float bias = brel[nt * 16 + m16];
#pragma unroll
    for (int mt = 0; mt < 2; ++mt) {
      int row0 = nodeBase + mt * 16 + quad * 4;
#pragma unroll
      for (int r = 0; r < 4; ++r) {
        int row = row0 + r;
        if (row < N)
          out[(size_t)row * F + nt * 16 + m16] = fmaxf(acc[mt][s][r] + bias, 0.f);
      }
    }
  }
}

// ===========================================================================
// Fallback A: proven R7 3-dispatch path (memset -> prep_bin -> agg_gemm)
// ===========================================================================
__global__ __launch_bounds__(256) void prep_bin_kernel(
    const float2* __restrict__ x, const float2* __restrict__ w0,
    const float2* __restrict__ w1, const int* __restrict__ ei,
    unsigned* __restrict__ xb, unsigned* __restrict__ wb,
    int* __restrict__ binCursor, unsigned* __restrict__ bin,
    int E, int NB, int n2x, int n2w) {
  const int tid0 = blockIdx.x * blockDim.x + threadIdx.x;
  const int stride = gridDim.x * blockDim.x;
  const int totalc = n2x + 2 * n2w;
  for (int i = tid0; i < totalc; i += stride) {
    if (i < n2x) xb[i] = pack2(x[i]);
    else if (i < n2x + n2w) wb[i - n2x] = pack2(w0[i - n2x]);
    else wb[i - n2x] = pack2(w1[i - n2x - n2w]);
  }
  const int part = blockIdx.x & (NPARTS - 1);
  for (int e = tid0; e < E; e += stride) {
    unsigned src = (unsigned)ei[e];
    unsigned dst = (unsigned)ei[E + e];
    int cell = part * NB + (int)(dst >> 5);
    int slot = atomicAdd(&binCursor[cell], 1);
    if (slot < CAP) bin[(size_t)cell * CAP + slot] = (dst << 16) | src;
  }
}

__global__ __launch_bounds__(256) void agg_gemm_kernel(
    const unsigned* __restrict__ xb, const unsigned* __restrict__ bin,
    const int* __restrict__ binCursor, const __bf16* __restrict__ wb,
    const float* __restrict__ brel, float* __restrict__ out, int N, int NB) {
  __shared__ int cntS[NPB];
  __shared__ int offS[NPB];
  __shared__ int curS[NPB];
  __shared__ unsigned short eLds[CAPB];
  __shared__ unsigned aLds[NPB * AST];
  const int b = blockIdx.x;
  const int t = threadIdx.x;
  if (t < NPB) cntS[t] = 0;
  __syncthreads();
  unsigned kreg[NPARTS];
  int cnt_p[NPARTS];
#pragma unroll
  for (int p = 0; p < NPARTS; ++p) {
    int cell = p * NB + b;
    int c = min(binCursor[cell], CAP);
    cnt_p[p] = c;
    kreg[p] = (t < c) ? bin[(size_t)cell * CAP + t] : 0u;
  }
#pragma unroll
  for (int p = 0; p < NPARTS; ++p) {
    if (t < cnt_p[p]) atomicAdd(&cntS[(kreg[p] >> 16) & (NPB - 1)], 1);
  }
  __syncthreads();
  if (t < 64) {
    int v = (t < NPB) ? cntS[t] : 0;
    int incl = v;
#pragma unroll
    for (int off = 1; off < NPB; off <<= 1) {
      int u = __shfl_up(incl, off);
      if (t >= off) incl += u;
    }
    if (t < NPB) {
      offS[t] = incl - v;
      curS[t] = incl - v;
    }
  }
  __syncthreads();
#pragma unroll
  for (int p = 0; p < NPARTS; ++p) {
    if (t < cnt_p[p]) {
      int d = (kreg[p] >> 16) & (NPB - 1);
      int pos = atomicAdd(&curS[d], 1);
      if (pos < CAPB) eLds[pos] = (unsigned short)(kreg[p] & 0xffffu);
    }
  }
  __syncthreads();
  const int wave = t >> 6;
  const int lane = t & 63;
  const int nodeBase = b * NPB;
#pragma unroll
  for (int di = wave; di < NPB; di += 4) {
    float ax = 0.f, ay = 0.f;
    int beg = min(offS[di], CAPB);
    int end = min(offS[di] + cntS[di], CAPB);
    int e = beg;
    for (; e + 3 < end; e += 4) {
      int s0 = eLds[e + 0];
      int s1 = eLds[e + 1];
      int s2 = eLds[e + 2];
      int s3 = eLds[e + 3];
      unsigned v0 = xb[(size_t)s0 * 64 + lane];
      unsigned v1 = xb[(size_t)s1 * 64 + lane];
      unsigned v2 = xb[(size_t)s2 * 64 + lane];
      unsigned v3 = xb[(size_t)s3 * 64 + lane];
      upk(v0, ax, ay);
      upk(v1, ax, ay);
      upk(v2, ax, ay);
      upk(v3, ax, ay);
    }
    for (; e < end; ++e) upk(xb[(size_t)eLds[e] * 64 + lane], ax, ay);
    aLds[di * AST + lane] = f32_to_bf16_rne(ax) | (f32_to_bf16_rne(ay) << 16);
  }
  __syncthreads();
  const int m16 = lane & 15;
  const int quad = lane >> 4;
  const f32x4 zero4 = {0.f, 0.f, 0.f, 0.f};
  const bf16x8 zero8 = {};
  f32x4 acc[2][2];
#pragma unroll
  for (int mt = 0; mt < 2; ++mt)
#pragma unroll
    for (int s = 0; s < 2; ++s) acc[mt][s] = zero4;
#pragma unroll
  for (int ph = 0; ph < 2; ++ph) {
    const __bf16* __restrict__ W = wb + (size_t)ph * F * F;
#pragma unroll
    for (int k0 = 0; k0 < F; k0 += 32) {
      const int kcol = k0 + 8 * quad;
      bf16x8 a[2], bw[2];
#pragma unroll
      for (int mt = 0; mt < 2; ++mt) {
        if (ph == 0) {
          a[mt] = *(const bf16x8*)&aLds[(mt * 16 + m16) * AST + (kcol >> 1)];
        } else {
          int row = nodeBase + mt * 16 + m16;
          a[mt] = (row < N)
                      ? *(const bf16x8*)((const __bf16*)xb + (size_t)row * F + kcol)
                      : zero8;
        }
      }
#pragma unroll
      for (int s = 0; s < 2; ++s) {
        int nt = wave * 2 + s;
        bw[s] = *(const bf16x8*)(W + (size_t)(nt * 16 + m16) * F + kcol);
      }
#pragma unroll
      for (int mt = 0; mt < 2; ++mt)
#pragma unroll
        for (int s = 0; s < 2; ++s)
          acc[mt][s] = __builtin_amdgcn_mfma_f32_16x16x32_bf16(
              a[mt], bw[s], acc[mt][s], 0, 0, 0);
    }
  }
#pragma unroll
  for (int s = 0; s < 2; ++s) {
    int nt = wave * 2 + s;
    float bias = brel[nt * 16 + m16];
#pragma unroll
    for (int mt = 0; mt < 2; ++mt) {
      int row0 = nodeBase + mt * 16 + quad * 4;
#pragma unroll
      for (int r = 0; r < 4; ++r) {
        int row = row0 + r;
        if (row < N)
          out[(size_t)row * F + nt * 16 + m16] = fmaxf(acc[mt][s][r] + bias, 0.f);
      }
    }
  }
}

// ===========================================================================
// Fallback B (tiny ws): fp32 atomics into out + fused fp32 GEMM in-place
// ===========================================================================
__global__ __launch_bounds__(256) void scatter_add_kernel(
    const float4* __restrict__ x4, const int* __restrict__ ei,
    float* __restrict__ agg, int E) {
  int gid = blockIdx.x * blockDim.x + threadIdx.x;
  if (gid >= E * 32) return;
  int e = gid >> 5, q = gid & 31;
  float4 v = x4[(size_t)ei[e] * 32 + q];
  float* a = agg + (size_t)ei[E + e] * F + q * 4;
  atomicAdd(a + 0, v.x);
  atomicAdd(a + 1, v.y);
  atomicAdd(a + 2, v.z);
  atomicAdd(a + 3, v.w);
}

#define ROWS_PER_BLOCK 64
#define SA_STRIDE 36
#define SW_STRIDE 132

__global__ __launch_bounds__(256) void gemm_fused_kernel(
    const float* __restrict__ agg, const float* __restrict__ x,
    const float* __restrict__ Wrel, const float* __restrict__ Wroot,
    const float* __restrict__ brel, float* __restrict__ out, int N) {
  __shared__ float sA[ROWS_PER_BLOCK * SA_STRIDE];
  __shared__ float sW[32 * SW_STRIDE];
  const int tid = threadIdx.x;
  const int j0 = (tid & 31) * 4;
  const int r0 = (tid >> 5) * 8;
  const int rowBase = blockIdx.x * ROWS_PER_BLOCK;
  float acc[8][4];
#pragma unroll
  for (int r = 0; r < 8; ++r)
#pragma unroll
    for (int c = 0; c < 4; ++c) acc[r][c] = 0.0f;
  for (int phase = 0; phase < 2; ++phase) {
    const float* __restrict__ A = phase ? x : agg;
    const float* __restrict__ W = phase ? Wroot : Wrel;
    for (int kc = 0; kc < F; kc += 32) {
#pragma unroll
      for (int idx = tid; idx < 512; idx += 256) {
        int row = idx >> 3, k4 = idx & 7;
        float4 v = make_float4(0.f, 0.f, 0.f, 0.f);
        int grow = rowBase + row;
        if (grow < N) v = *(const float4*)&A[(size_t)grow * F + kc + k4 * 4];
        *(float4*)&sA[row * SA_STRIDE + k4 * 4] = v;
      }
#pragma unroll
      for (int idx = tid; idx < 4096; idx += 256) {
        int j = idx >> 5, kk = idx & 31;
        sW[kk * SW_STRIDE + j] = W[j * F + kc + kk];
      }
      __syncthreads();
#pragma unroll
      for (int kk = 0; kk < 32; ++kk) {
        float4 w = *(const float4*)&sW[kk * SW_STRIDE + j0];
#pragma unroll
        for (int r = 0; r < 8; ++r) {
          float a = sA[(r0 + r) * SA_STRIDE + kk];
          acc[r][0] = fmaf(a, w.x, acc[r][0]);
          acc[r][1] = fmaf(a, w.y, acc[r][1]);
          acc[r][2] = fmaf(a, w.z, acc[r][2]);
          acc[r][3] = fmaf(a, w.w, acc[r][3]);
        }
      }
      __syncthreads();
    }
  }
  float b0 = brel[j0], b1 = brel[j0 + 1], b2 = brel[j0 + 2], b3 = brel[j0 + 3];
#pragma unroll
  for (int r = 0; r < 8; ++r) {
    int row = rowBase + r0 + r;
    if (row < N) {
      float4 v;
      v.x = fmaxf(acc[r][0] + b0, 0.0f);
      v.y = fmaxf(acc[r][1] + b1, 0.0f);
      v.z = fmaxf(acc[r][2] + b2, 0.0f);
      v.w = fmaxf(acc[r][3] + b3, 0.0f);
      *(float4*)&out[(size_t)row * F + j0] = v;
    }
  }
}

extern "C" void kernel_launch(void* const* d_in, const int* in_sizes, int n_in,
                              void* d_out, int out_size, void* d_ws, size_t ws_size,
                              hipStream_t stream) {
  const float* x     = (const float*)d_in[0];
  const int*   ei    = (const int*)d_in[1];
  const float* Wrel  = (const float*)d_in[2];
  const float* brel  = (const float*)d_in[3];
  const float* Wroot = (const float*)d_in[4];
  float* out = (float*)d_out;

  const int N = in_sizes[0] / F;       // 50000
  const int E = in_sizes[1] / 2;       // 800000
  const int NB = (N + NPB - 1) / NPB;  // 1563 buckets

  size_t xbBytes  = ((size_t)N * F * 2 + 255) & ~(size_t)255;
  size_t wBytes   = ((size_t)2 * F * F * 2 + 255) & ~(size_t)255;
  size_t curBytes = ((size_t)NPARTS * NB * sizeof(int) + 255) & ~(size_t)255;
  size_t binBytes = ((size_t)NPARTS * NB * CAP * sizeof(unsigned) + 255) & ~(size_t)255;
  size_t needBin  = curBytes + binBytes + xbBytes + wBytes;

  if (ws_size >= needBin) {
    int*      binCursor = (int*)d_ws;
    unsigned* bin = (unsigned*)((char*)d_ws + curBytes);
    unsigned* xb  = (unsigned*)((char*)d_ws + curBytes + binBytes);
    unsigned* wb  = (unsigned*)((char*)d_ws + curBytes + binBytes + xbBytes);

    int n2x = N * (F / 2);
    int n2w = F * F / 2;

    int maxBlocksPerCU = 0;
    hipError_t qerr = hipOccupancyMaxActiveBlocksPerMultiprocessor(
        &maxBlocksPerCU, (const void*)mega_kernel, 256, 0);
    bool coopOk = (qerr == hipSuccess) && (maxBlocksPerCU * 256 >= NB);

    if (coopOk) {
      const float2* xa = (const float2*)x;
      const float2* w0 = (const float2*)Wrel;
      const float2* w1 = (const float2*)Wroot;
      void* args[] = {(void*)&xa, (void*)&w0, (void*)&w1, (void*)&ei,
                      (void*)&xb, (void*)&wb, (void*)&binCursor, (void*)&bin,
                      (void*)&brel, (void*)&out,
                      (void*)&N, (void*)&E, (void*)&NB, (void*)&n2x, (void*)&n2w};
      hipError_t lerr = hipLaunchCooperativeKernel(
          (const void*)mega_kernel, dim3(NB), dim3(256), args, 0, stream);
      if (lerr == hipSuccess) return;
    }

    hipMemsetAsync(binCursor, 0, (size_t)NPARTS * NB * sizeof(int), stream);
    prep_bin_kernel<<<2048, 256, 0, stream>>>(
        (const float2*)x, (const float2*)Wrel, (const float2*)Wroot, ei, xb, wb,
        binCursor, bin, E, NB, n2x, n2w);
    agg_gemm_kernel<<<NB, 256, 0, stream>>>(xb, bin, binCursor,
                                            (const __bf16*)wb, brel, out, N, NB);
  } else {
    hipMemsetAsync(out, 0, (size_t)N * F * sizeof(float), stream);
    long long total = (long long)E * 32;
    scatter_add_kernel<<<(int)((total + 255) / 256), 256, 0, stream>>>(
        (const float4*)x, ei, out, E);
    gemm_fused_kernel<<<(N + ROWS_PER_BLOCK - 1) / ROWS_PER_BLOCK, 256, 0,
                        stream>>>(out, x, Wrel, Wroot, brel, out, N);
  }
}